// Round 9
// baseline (537.813 us; speedup 1.0000x reference)
//
#include <hip/hip_runtime.h>
#include <cstdio>
#include <cstdint>

typedef _Float16 f16x8 __attribute__((ext_vector_type(8)));
typedef float f32x4 __attribute__((ext_vector_type(4)));

__device__ inline unsigned short f2bf(float f) {  // fp32 -> bf16 RNE
  unsigned u = __float_as_uint(f);
  u += 0x7fffu + ((u >> 16) & 1u);
  return (unsigned short)(u >> 16);
}
__device__ inline float bf2f(unsigned short h) {
  return __uint_as_float(((unsigned)h) << 16);
}
__device__ inline unsigned short f2h(float f) {   // fp32 -> fp16 RNE (bits)
  union { _Float16 h; unsigned short u; } cv;
  cv.h = (_Float16)f;
  return cv.u;
}

#define EPB 8192

// ======= fused prep: psum zero, feat->bf16, W->fp16^T, gbound, bhist ======
// hist blocks ALSO accumulate per-node cnt/wsum via global atomics
// (L2-resident 800KB arrays) -> k_bprocA pass eliminated entirely.

__global__ __launch_bounds__(256)
void k_prep0(float* __restrict__ psum,
             const float* __restrict__ feature, ushort* __restrict__ featb,
             const float* __restrict__ W1, ushort* __restrict__ w1h,
             const float* __restrict__ W2, ushort* __restrict__ w2h,
             const float* __restrict__ W3, ushort* __restrict__ w3h,
             const int* __restrict__ pb, int* __restrict__ gs,
             const int* __restrict__ dst, const float* __restrict__ ew,
             int* __restrict__ H, int* __restrict__ rs,
             int* __restrict__ cntN, float* __restrict__ wsumN,
             int BC, int NF, int F, int D2, int D3,
             int N, int B, int NB, int E,
             int nB, int nC, int nD, int nG) {
  __shared__ int hist[512];
  int b = blockIdx.x;
  int t = threadIdx.x;
  if (b < nB) {
    int i = b * 256 + t;
    if (i < BC) psum[i] = 0.f;
  } else if (b < nB + nC) {
    int base = ((b - nB) * 256 + t) * 4;
    if (base < NF) {
      float4 v = *reinterpret_cast<const float4*>(feature + base);
      ushort4 h;
      h.x = f2bf(v.x); h.y = f2bf(v.y); h.z = f2bf(v.z); h.w = f2bf(v.w);
      *reinterpret_cast<ushort4*>(featb + base) = h;
    }
  } else if (b < nB + nC + nD) {
    int idx = (b - nB - nC) * 256 + t;
    int s1 = F * F, s2 = s1 + F * D2, s3 = s2 + D2 * D3;
    if (idx < s1) {
      int k = idx / F, n = idx - k * F;
      w1h[(size_t)n * F + k] = f2h(W1[idx]);
    } else if (idx < s2) {
      int i2 = idx - s1; int k = i2 / D2, n = i2 - k * D2;
      w2h[(size_t)n * F + k] = f2h(W2[i2]);
    } else if (idx < s3) {
      int i3 = idx - s2; int k = i3 / D3, n = i3 - k * D3;
      w3h[(size_t)n * D2 + k] = f2h(W3[i3]);
    }
  } else if (b < nB + nC + nD + nG) {
    int bb = (b - nB - nC - nD) * 256 + t;
    if (bb == 0) rs[N] = E;            // row-end sentinel (absolute)
    if (bb <= B) {
      int lo = 0, hi = N;
      while (lo < hi) {
        int mid = (lo + hi) >> 1;
        if (pb[mid] < bb) lo = mid + 1; else hi = mid;
      }
      gs[bb] = lo;
    }
  } else {
    const int bi = b - nB - nC - nD - nG;
    for (int i = t; i < NB; i += 256) hist[i] = 0;
    __syncthreads();
    const int base = bi * EPB + t;
#pragma unroll
    for (int j = 0; j < EPB / 256; j++) {
      int e = base + 256 * j;
      if (e < E) {
        int d = dst[e];
        atomicAdd(&hist[d >> 8], 1);
        atomicAdd(&cntN[d], 1);
        atomicAdd(&wsumN[d], ew[e]);
      }
    }
    __syncthreads();
    for (int i = t; i < NB; i += 256) H[(size_t)bi * NB + i] = hist[i];
  }
}

// ===== fused scans (both depend only on prep0): =====
// range [0,nchT): chunk-local exclusive scan of H (bin-major) -> S, bsb
// range [nchT,nchT+nchN): chunk-local scan of cntN -> rs, bsum + dinv/sn

__global__ __launch_bounds__(256)
void k_scans(const int* __restrict__ H, int* __restrict__ S,
             int* __restrict__ bsb,
             const int* __restrict__ cntN, const float* __restrict__ wsumN,
             int* __restrict__ rs, int* __restrict__ bsum,
             float* __restrict__ dinv, float* __restrict__ sn,
             int NB, int NBLK, int T, int N, int nchT) {
  __shared__ int sh[256];
  const int t = threadIdx.x;
  if ((int)blockIdx.x < nchT) {
    const int base = blockIdx.x * 1024;
    int v[4]; int s = 0;
#pragma unroll
    for (int j = 0; j < 4; j++) {
      int idx = base + t * 4 + j;
      if (idx < T) {
        int bin = idx / NBLK, bi = idx - bin * NBLK;
        v[j] = H[(size_t)bi * NB + bin];
      } else v[j] = 0;
      s += v[j];
    }
    sh[t] = s;
    __syncthreads();
    for (int off = 1; off < 256; off <<= 1) {
      int x = (t >= off) ? sh[t - off] : 0;
      __syncthreads();
      sh[t] += x;
      __syncthreads();
    }
    int run = sh[t] - s;
#pragma unroll
    for (int j = 0; j < 4; j++) {
      int idx = base + t * 4 + j;
      if (idx < T) S[idx] = run;
      run += v[j];
    }
    if (t == 255) bsb[blockIdx.x] = sh[255];
  } else {
    const int base = (blockIdx.x - nchT) * 1024;
    int v[4]; int s = 0;
#pragma unroll
    for (int j = 0; j < 4; j++) {
      int idx = base + t * 4 + j;
      if (idx < N) {
        v[j] = cntN[idx];
        double deg = 1.0 + (double)wsumN[idx];
        float r = (float)(1.0 / sqrt(deg));
        dinv[idx] = r;
        sn[idx] = r * r;
      } else v[j] = 0;
      s += v[j];
    }
    sh[t] = s;
    __syncthreads();
    for (int off = 1; off < 256; off <<= 1) {
      int x = (t >= off) ? sh[t - off] : 0;
      __syncthreads();
      sh[t] += x;
      __syncthreads();
    }
    int run = sh[t] - s;
#pragma unroll
    for (int j = 0; j < 4; j++) {
      int idx = base + t * 4 + j;
      if (idx < N) rs[idx] = run;
      run += v[j];
    }
    if (t == 255) bsum[blockIdx.x - nchT] = sh[255];
  }
}

// build exclusive chunk-prefix (<=512 chunks) in LDS: load + thread-0 scan
__device__ inline void build_prefix(const int* __restrict__ bsum, int nch,
                                    int* __restrict__ pre, int t) {
  for (int i = t; i < nch; i += 256) pre[i] = bsum[i];
  __syncthreads();
  if (t == 0) {
    int run = 0;
    for (int i = 0; i < nch; i++) { int v = pre[i]; pre[i] = run; run += v; }
  }
  __syncthreads();
}

// scatter edges into bucket-sorted order; ld packed into ssw.x bits 24..31
__global__ __launch_bounds__(256)
void k_bscatter(const int* __restrict__ src, const int* __restrict__ dst,
                const float* __restrict__ ew, const int* __restrict__ S,
                const int* __restrict__ bsb,
                int2* __restrict__ ssw,
                int NB, int NBLK, int E, int nchT) {
  __shared__ int cnt[512];
  __shared__ int sbase[512];
  __shared__ int pre[512];
  const int t = threadIdx.x, bi = blockIdx.x;
  build_prefix(bsb, nchT, pre, t);
  for (int i = t; i < NB; i += 256) {
    cnt[i] = 0;
    int j = i * NBLK + bi;
    sbase[i] = S[j] + pre[j >> 10];
  }
  __syncthreads();
  const int base = bi * EPB + t;
#pragma unroll
  for (int j = 0; j < EPB / 256; j++) {
    int e = base + 256 * j;
    if (e < E) {
      int d = dst[e];
      int bin = d >> 8;
      int r = atomicAdd(&cnt[bin], 1);
      int pos = sbase[bin] + r;
      ssw[pos] = make_int2(src[e] | ((d & 255) << 24), __float_as_int(ew[e]));
    }
  }
}

// per-bucket pass B: epack fill at absolute rs positions; writes ABSOLUTE rs
__global__ __launch_bounds__(256)
void k_bprocB(const int2* __restrict__ ssw,
              const int* __restrict__ S, const int* __restrict__ bsb,
              int* __restrict__ rs, const int* __restrict__ bsumN,
              const float* __restrict__ dinv,
              int2* __restrict__ epack,
              int NB, int NBLK, int N, int E, int nchT, int nchN) {
  __shared__ int cnt[256];
  __shared__ float sdv[256];
  __shared__ int srs[256];
  __shared__ int preT[512];
  __shared__ int preN[128];
  const int t = threadIdx.x, bin = blockIdx.x;
  for (int i = t; i < nchT; i += 256) preT[i] = bsb[i];
  for (int i = t; i < nchN; i += 256) preN[i] = bsumN[i];
  __syncthreads();
  if (t == 0) {
    int run = 0;
    for (int i = 0; i < nchT; i++) { int v = preT[i]; preT[i] = run; run += v; }
    run = 0;
    for (int i = 0; i < nchN; i++) { int v = preN[i]; preN[i] = run; run += v; }
  }
  __syncthreads();
  cnt[t] = 0;
  int n = bin * 256 + t;
  sdv[t] = (n < N) ? dinv[n] : 0.f;
  int rabs = 0;
  if (n < N) {
    rabs = rs[n] + preN[n >> 10];
    rs[n] = rabs;                      // absolute write-back
  }
  srs[t] = rabs;
  __syncthreads();
  int j0 = bin * NBLK;
  const int start = S[j0] + preT[j0 >> 10];
  int end = E;
  if (bin + 1 < NB) { int j1 = (bin + 1) * NBLK; end = S[j1] + preT[j1 >> 10]; }
  for (int p = start + t; p < end; p += 256) {
    int2 sw = ssw[p];
    int ld = (unsigned)sw.x >> 24;
    int sidx = sw.x & 0x00FFFFFF;
    int r = atomicAdd(&cnt[ld], 1);
    float w = dinv[sidx] * __int_as_float(sw.y) * sdv[ld];
    epack[srs[ld] + r] = make_int2(sidx, __float_as_int(w));
  }
}

// ================= CSR gather aggregation (bf16 in, fp16 out) ======

__device__ inline void bf8_fma(const int4 v, float w, float* acc) {
  acc[0] = fmaf(__uint_as_float((unsigned)v.x << 16), w, acc[0]);
  acc[1] = fmaf(__uint_as_float((unsigned)v.x & 0xffff0000u), w, acc[1]);
  acc[2] = fmaf(__uint_as_float((unsigned)v.y << 16), w, acc[2]);
  acc[3] = fmaf(__uint_as_float((unsigned)v.y & 0xffff0000u), w, acc[3]);
  acc[4] = fmaf(__uint_as_float((unsigned)v.z << 16), w, acc[4]);
  acc[5] = fmaf(__uint_as_float((unsigned)v.z & 0xffff0000u), w, acc[5]);
  acc[6] = fmaf(__uint_as_float((unsigned)v.w << 16), w, acc[6]);
  acc[7] = fmaf(__uint_as_float((unsigned)v.w & 0xffff0000u), w, acc[7]);
}

template<int LOG2L>
__global__ __launch_bounds__(256)
void k_aggregate_b(const ushort* __restrict__ Xb, const int* __restrict__ rs,
                   const int2* __restrict__ epack, const float* __restrict__ sn,
                   ushort* __restrict__ AH, int N) {
  const int t = blockIdx.x * blockDim.x + threadIdx.x;
  const int row = t >> LOG2L;
  if (row >= N) return;
  const int L = 1 << LOG2L;
  const int D = L << 3;
  const int c = (t & (L - 1)) << 3;
  const ushort* __restrict__ Xc = Xb + c;   // column-shifted base

  float acc[8];
  {
    int4 v = *reinterpret_cast<const int4*>(Xc + (size_t)row * D);
    float s = sn[row];
    acc[0] = s * __uint_as_float((unsigned)v.x << 16);
    acc[1] = s * __uint_as_float((unsigned)v.x & 0xffff0000u);
    acc[2] = s * __uint_as_float((unsigned)v.y << 16);
    acc[3] = s * __uint_as_float((unsigned)v.y & 0xffff0000u);
    acc[4] = s * __uint_as_float((unsigned)v.z << 16);
    acc[5] = s * __uint_as_float((unsigned)v.z & 0xffff0000u);
    acc[6] = s * __uint_as_float((unsigned)v.w << 16);
    acc[7] = s * __uint_as_float((unsigned)v.w & 0xffff0000u);
  }
  const int p0 = rs[row], pe = rs[row + 1];
  int i = p0;
  if ((i & 1) && i < pe) {          // peel to int4 alignment
    int2 e = epack[i];
    int4 v = *reinterpret_cast<const int4*>(Xc + (size_t)e.x * D);
    bf8_fma(v, __int_as_float(e.y), acc);
    i++;
  }
  for (; i + 8 <= pe; i += 8) {     // 8 gathers in flight
    int4 ea = *reinterpret_cast<const int4*>(&epack[i]);
    int4 eb = *reinterpret_cast<const int4*>(&epack[i + 2]);
    int4 ec = *reinterpret_cast<const int4*>(&epack[i + 4]);
    int4 ed = *reinterpret_cast<const int4*>(&epack[i + 6]);
    int4 v0 = *reinterpret_cast<const int4*>(Xc + (size_t)ea.x * D);
    int4 v1 = *reinterpret_cast<const int4*>(Xc + (size_t)ea.z * D);
    int4 v2 = *reinterpret_cast<const int4*>(Xc + (size_t)eb.x * D);
    int4 v3 = *reinterpret_cast<const int4*>(Xc + (size_t)eb.z * D);
    int4 v4 = *reinterpret_cast<const int4*>(Xc + (size_t)ec.x * D);
    int4 v5 = *reinterpret_cast<const int4*>(Xc + (size_t)ec.z * D);
    int4 v6 = *reinterpret_cast<const int4*>(Xc + (size_t)ed.x * D);
    int4 v7 = *reinterpret_cast<const int4*>(Xc + (size_t)ed.z * D);
    bf8_fma(v0, __int_as_float(ea.y), acc);
    bf8_fma(v1, __int_as_float(ea.w), acc);
    bf8_fma(v2, __int_as_float(eb.y), acc);
    bf8_fma(v3, __int_as_float(eb.w), acc);
    bf8_fma(v4, __int_as_float(ec.y), acc);
    bf8_fma(v5, __int_as_float(ec.w), acc);
    bf8_fma(v6, __int_as_float(ed.y), acc);
    bf8_fma(v7, __int_as_float(ed.w), acc);
  }
  if (i + 4 <= pe) {                // remainder 4
    int4 ea = *reinterpret_cast<const int4*>(&epack[i]);
    int4 eb = *reinterpret_cast<const int4*>(&epack[i + 2]);
    int4 v0 = *reinterpret_cast<const int4*>(Xc + (size_t)ea.x * D);
    int4 v1 = *reinterpret_cast<const int4*>(Xc + (size_t)ea.z * D);
    int4 v2 = *reinterpret_cast<const int4*>(Xc + (size_t)eb.x * D);
    int4 v3 = *reinterpret_cast<const int4*>(Xc + (size_t)eb.z * D);
    bf8_fma(v0, __int_as_float(ea.y), acc);
    bf8_fma(v1, __int_as_float(ea.w), acc);
    bf8_fma(v2, __int_as_float(eb.y), acc);
    bf8_fma(v3, __int_as_float(eb.w), acc);
    i += 4;
  }
  if (i + 2 <= pe) {                // remainder pair
    int4 e2 = *reinterpret_cast<const int4*>(&epack[i]);
    int4 v0 = *reinterpret_cast<const int4*>(Xc + (size_t)e2.x * D);
    int4 v1 = *reinterpret_cast<const int4*>(Xc + (size_t)e2.z * D);
    bf8_fma(v0, __int_as_float(e2.y), acc);
    bf8_fma(v1, __int_as_float(e2.w), acc);
    i += 2;
  }
  if (i < pe) {                     // remainder single
    int2 e = epack[i];
    int4 v = *reinterpret_cast<const int4*>(Xc + (size_t)e.x * D);
    bf8_fma(v, __int_as_float(e.y), acc);
  }
  ushort h[8];
#pragma unroll
  for (int j = 0; j < 8; j++) h[j] = f2h(acc[j]);
  size_t o = (size_t)row * D + c;
  *reinterpret_cast<ushort4*>(AH + o)     = make_ushort4(h[0], h[1], h[2], h[3]);
  *reinterpret_cast<ushort4*>(AH + o + 4) = make_ushort4(h[4], h[5], h[6], h[7]);
}

// ====== fp16 MFMA GEMM, B-in-registers, multi-tile blocks ======

template<int KT, int TPB>
__global__ __launch_bounds__(256, 3)
void k_gemm_rb(const ushort* __restrict__ Ah, const ushort* __restrict__ Bh,
               const float* __restrict__ bias, ushort* __restrict__ Y,
               int N, int D) {
  constexpr int NT = 64;
  constexpr int NK = KT / 32;
  const int t = threadIdx.x;
  const int wave = t >> 6, lane = t & 63;
  const int quad = lane >> 4, l16 = lane & 15;
  const int n0 = blockIdx.x * NT;
  const int mbase = blockIdx.y * (TPB * 128);

  f16x8 bf[NK][4];
#pragma unroll
  for (int k0 = 0; k0 < NK; k0++)
#pragma unroll
    for (int ni = 0; ni < 4; ni++)
      bf[k0][ni] = *reinterpret_cast<const f16x8*>(
          Bh + (size_t)(n0 + ni * 16 + l16) * KT + k0 * 32 + quad * 8);

  float bv[4];
#pragma unroll
  for (int ni = 0; ni < 4; ni++) bv[ni] = bias[n0 + ni * 16 + l16];

#pragma unroll 1
  for (int tile = 0; tile < TPB; tile++) {
    const int rt = mbase + tile * 128 + wave * 32 + l16;
    if (mbase + tile * 128 >= N) break;   // block-uniform
    int r0 = rt;      if (r0 >= N) r0 = N - 1;
    int r1 = rt + 16; if (r1 >= N) r1 = N - 1;
    const ushort* __restrict__ A0 = Ah + (size_t)r0 * KT + quad * 8;
    const ushort* __restrict__ A1 = Ah + (size_t)r1 * KT + quad * 8;

    f16x8 a0[NK], a1[NK];
#pragma unroll
    for (int k0 = 0; k0 < NK; k0++) {
      a0[k0] = *reinterpret_cast<const f16x8*>(A0 + k0 * 32);
      a1[k0] = *reinterpret_cast<const f16x8*>(A1 + k0 * 32);
    }

    f32x4 acc[2][4];
#pragma unroll
    for (int mi = 0; mi < 2; mi++)
#pragma unroll
      for (int ni = 0; ni < 4; ni++) acc[mi][ni] = (f32x4){0.f, 0.f, 0.f, 0.f};

#pragma unroll
    for (int k0 = 0; k0 < NK; k0++)
#pragma unroll
      for (int ni = 0; ni < 4; ni++) {
        acc[0][ni] = __builtin_amdgcn_mfma_f32_16x16x32_f16(a0[k0], bf[k0][ni], acc[0][ni], 0, 0, 0);
        acc[1][ni] = __builtin_amdgcn_mfma_f32_16x16x32_f16(a1[k0], bf[k0][ni], acc[1][ni], 0, 0, 0);
      }

    const int rb0 = mbase + tile * 128 + wave * 32 + quad * 4;
#pragma unroll
    for (int mi = 0; mi < 2; mi++) {
      int rb = rb0 + mi * 16;
#pragma unroll
      for (int ni = 0; ni < 4; ni++) {
        int col = n0 + ni * 16 + l16;
#pragma unroll
        for (int r = 0; r < 4; r++) {
          int row = rb + r;
          if (row < N)
            Y[(size_t)row * D + col] = f2bf(fmaxf(acc[mi][ni][r] + bv[ni], 0.f));
        }
      }
    }
  }
}

// ================= pooling: one (graph, split) per block, branch-free =====

#define PSPLIT 4

__global__ void k_pool(const ushort* __restrict__ X3b, const float* __restrict__ feat,
                       const int* __restrict__ gs, float* __restrict__ psum,
                       int D3, int F) {
  const int c = threadIdx.x;
  const int C = D3 + F;
  const int b = blockIdx.y;
  const int sp = blockIdx.x;
  const int s0 = gs[b], e0 = gs[b + 1];
  const int len = e0 - s0;
  if (len <= 0) return;
  const int chunk = (len + PSPLIT - 1) / PSPLIT;
  const int s = s0 + sp * chunk;
  int e = s + chunk; if (e > e0) e = e0;
  if (s >= e) return;
  const int n = e - s;
  float a0 = 0.f, a1 = 0.f, a2 = 0.f, a3 = 0.f;
  float a4 = 0.f, a5 = 0.f, a6 = 0.f, a7 = 0.f;
  if (c < D3) {
    const ushort* p = X3b + (size_t)s * D3 + c;
    int i = 0;
    for (; i + 8 <= n; i += 8) {
      a0 += bf2f(p[0 * (size_t)D3]);
      a1 += bf2f(p[1 * (size_t)D3]);
      a2 += bf2f(p[2 * (size_t)D3]);
      a3 += bf2f(p[3 * (size_t)D3]);
      a4 += bf2f(p[4 * (size_t)D3]);
      a5 += bf2f(p[5 * (size_t)D3]);
      a6 += bf2f(p[6 * (size_t)D3]);
      a7 += bf2f(p[7 * (size_t)D3]);
      p += 8 * (size_t)D3;
    }
    for (; i < n; i++) { a0 += bf2f(*p); p += D3; }
  } else {
    const float* p = feat + (size_t)s * F + (c - D3);
    int i = 0;
    for (; i + 8 <= n; i += 8) {
      a0 += p[0 * (size_t)F];
      a1 += p[1 * (size_t)F];
      a2 += p[2 * (size_t)F];
      a3 += p[3 * (size_t)F];
      a4 += p[4 * (size_t)F];
      a5 += p[5 * (size_t)F];
      a6 += p[6 * (size_t)F];
      a7 += p[7 * (size_t)F];
      p += 8 * (size_t)F;
    }
    for (; i < n; i++) { a0 += *p; p += F; }
  }
  float tot = ((a0 + a1) + (a2 + a3)) + ((a4 + a5) + (a6 + a7));
  atomicAdd(&psum[(size_t)b * C + c], tot);
}

// ================= FC head (gc normalization fused into fc1) ==============

__global__ __launch_bounds__(256)
void k_fc1(const float* __restrict__ psum, const int* __restrict__ gs,
           const float* __restrict__ Wf1, const float* __restrict__ bf1,
           float* __restrict__ hidden, int C, int Hh) {
  const int b = blockIdx.y;
  __shared__ float gcs[384];
  float invc = 1.f / fmaxf((float)(gs[b + 1] - gs[b]), 1.f);
  for (int c = threadIdx.x; c < C; c += 256)
    gcs[c] = psum[(size_t)b * C + c] * invc;
  __syncthreads();
  const int j = blockIdx.x * 256 + threadIdx.x;
  if (j >= Hh) return;
  const float* w = Wf1 + j;
  float a0 = 0.f, a1 = 0.f, a2 = 0.f, a3 = 0.f;
  int c = 0;
  for (; c + 4 <= C; c += 4) {
    a0 = fmaf(gcs[c + 0], w[(size_t)(c + 0) * Hh], a0);
    a1 = fmaf(gcs[c + 1], w[(size_t)(c + 1) * Hh], a1);
    a2 = fmaf(gcs[c + 2], w[(size_t)(c + 2) * Hh], a2);
    a3 = fmaf(gcs[c + 3], w[(size_t)(c + 3) * Hh], a3);
  }
  for (; c < C; c++) a0 = fmaf(gcs[c], w[(size_t)c * Hh], a0);
  float r = ((a0 + a1) + (a2 + a3)) + bf1[j];
  hidden[(size_t)b * Hh + j] = fmaxf(r, 0.f);
}

__global__ void k_fc2(const float* __restrict__ hidden, const float* __restrict__ Wf2,
                      const float* __restrict__ bf2, float* __restrict__ out, int Hh) {
  int b = blockIdx.x;
  int lane = threadIdx.x;  // 64
  double s = 0.0;
  for (int j = lane; j < Hh; j += 64) s += (double)hidden[(size_t)b * Hh + j] * (double)Wf2[j];
#pragma unroll
  for (int off = 32; off > 0; off >>= 1) s += __shfl_down(s, off);
  if (lane == 0) out[b] = (float)s + bf2[0];
}

// ================= launch =================

extern "C" void kernel_launch(void* const* d_in, const int* in_sizes, int n_in,
                              void* d_out, int out_size, void* d_ws, size_t ws_size,
                              hipStream_t stream) {
  const float* feature = (const float*)d_in[0];
  const int*   eidx    = (const int*)  d_in[1];
  const float* weight  = (const float*)d_in[2];
  const int*   pb      = (const int*)  d_in[3];
  const float* W1  = (const float*)d_in[4];
  const float* b1  = (const float*)d_in[5];
  const float* W2  = (const float*)d_in[6];
  const float* b2  = (const float*)d_in[7];
  const float* W3  = (const float*)d_in[8];
  const float* b3  = (const float*)d_in[9];
  const float* Wf1 = (const float*)d_in[10];
  const float* bf1 = (const float*)d_in[11];
  const float* Wf2 = (const float*)d_in[12];
  const float* bf2 = (const float*)d_in[13];

  const int F  = in_sizes[5];          // 64
  const int D2 = in_sizes[7];          // 128
  const int D3 = in_sizes[9];          // 256
  const int Hh = in_sizes[11];         // 1024
  const int N  = in_sizes[0] / F;      // 100000
  const int E  = in_sizes[1] / 2;      // 1200000
  const int B  = out_size;             // 256
  const int C  = D3 + F;               // 320

  const int* srcp = eidx;
  const int* dstp = eidx + E;

  const int NB   = (N + 255) / 256;        // buckets (<=512)
  const int NBLK = (E + EPB - 1) / EPB;    // edge blocks
  const int T    = NB * NBLK;              // scan length
  const int nchT = (T + 1023) / 1024;      // T-scan chunks (<=512)
  const int nchN = (N + 1023) / 1024;      // rs-scan chunks (<=128)

  auto al = [](size_t x) { return (x + 255) & ~(size_t)255; };
  size_t off = 0;
  auto alloc = [&](size_t bytes) { size_t o = off; off += al(bytes); return o; };
  size_t o_H     = alloc((size_t)T * 4);
  size_t o_S     = alloc((size_t)T * 4);
  size_t o_bsb   = alloc((size_t)nchT * 4);
  size_t o_ssw   = alloc((size_t)E * 8);
  size_t o_cw    = alloc((size_t)2 * N * 4);    // cntN | wsumN contiguous
  size_t o_dinv  = alloc((size_t)N * 4);
  size_t o_sn    = alloc((size_t)N * 4);
  size_t o_rs    = alloc((size_t)(N + 1) * 4);
  size_t o_bsum  = alloc((size_t)nchN * 4);
  size_t o_epack = alloc((size_t)E * 8);
  size_t o_featb = alloc((size_t)N * F  * 2);
  size_t o_x1b   = alloc((size_t)N * F  * 2);
  size_t o_x2b   = alloc((size_t)N * D2 * 2);
  size_t o_x3b   = alloc((size_t)N * D3 * 2);
  size_t o_aggh  = alloc((size_t)N * D2 * 2);   // fp16 (max K = 128)
  size_t o_w1h   = alloc((size_t)F  * F  * 2);
  size_t o_w2h   = alloc((size_t)F  * D2 * 2);
  size_t o_w3h   = alloc((size_t)D2 * D3 * 2);
  size_t o_psum  = alloc((size_t)B * C * 4);    // float
  size_t o_gs    = alloc((size_t)(B + 1) * 4);
  size_t o_hid   = alloc((size_t)B * Hh * 4);
  if (off > ws_size) {
    fprintf(stderr, "kernel_launch: workspace too small: need %zu, have %zu\n", off, ws_size);
    return;
  }

  char* ws = (char*)d_ws;
  int*    H     = (int*)  (ws + o_H);
  int*    S     = (int*)  (ws + o_S);
  int*    bsb   = (int*)  (ws + o_bsb);
  int2*   ssw   = (int2*) (ws + o_ssw);
  int*    cntN  = (int*)  (ws + o_cw);
  float*  wsumN = (float*)(ws + o_cw + (size_t)N * 4);
  float*  dinv  = (float*)(ws + o_dinv);
  float*  sn    = (float*)(ws + o_sn);
  int*    rs    = (int*)  (ws + o_rs);
  int*    bsum  = (int*)  (ws + o_bsum);
  int2*   epack = (int2*) (ws + o_epack);
  ushort* featb = (ushort*)(ws + o_featb);
  ushort* x1b   = (ushort*)(ws + o_x1b);
  ushort* x2b   = (ushort*)(ws + o_x2b);
  ushort* x3b   = (ushort*)(ws + o_x3b);
  ushort* aggh  = (ushort*)(ws + o_aggh);
  ushort* w1h   = (ushort*)(ws + o_w1h);
  ushort* w2h   = (ushort*)(ws + o_w2h);
  ushort* w3h   = (ushort*)(ws + o_w3h);
  float*  psum  = (float*) (ws + o_psum);
  int*    gs    = (int*)  (ws + o_gs);
  float*  hid   = (float*)(ws + o_hid);
  float*  out   = (float*)d_out;

  // ---- zero cnt/wsum (one memset, contiguous) ----
  hipMemsetAsync(ws + o_cw, 0, (size_t)2 * N * 4, stream);

  // ---- fused prep (+gbound +bhist +cnt/wsum atomics) ----
  const int BC = B * C, NF = N * F;
  const int nB = (BC + 255) / 256;
  const int nC = (NF / 4 + 255) / 256;
  const int nD = (F * F + F * D2 + D2 * D3 + 255) / 256;
  const int nG = (B + 1 + 255) / 256;
  k_prep0<<<nB + nC + nD + nG + NBLK, 256, 0, stream>>>(
      psum, feature, featb, W1, w1h, W2, w2h, W3, w3h,
      pb, gs, dstp, weight, H, rs, cntN, wsumN,
      BC, NF, F, D2, D3, N, B, NB, E, nB, nC, nD, nG);

  // ---- fused scans (both depend only on prep0) ----
  k_scans<<<nchT + nchN, 256, 0, stream>>>(
      H, S, bsb, cntN, wsumN, rs, bsum, dinv, sn, NB, NBLK, T, N, nchT);

  // ---- scatter + epack fill ----
  k_bscatter<<<NBLK, 256, 0, stream>>>(srcp, dstp, weight, S, bsb, ssw, NB, NBLK, E, nchT);
  k_bprocB  <<<NB, 256, 0, stream>>>(ssw, S, bsb, rs, bsum, dinv, epack, NB, NBLK, N, E, nchT, nchN);

  const int Mt = (N + 127) / 128;   // 128-row M-tiles

  // ---- layer 1: agg(featb)[N,64] @ W1[64,64] -> x1b (bf16) ----
  {
    int tot = N * (F / 8);
    k_aggregate_b<3><<<(tot + 255) / 256, 256, 0, stream>>>(featb, rs, epack, sn, aggh, N);
    dim3 g(1, Mt);
    k_gemm_rb<64, 1><<<g, 256, 0, stream>>>(aggh, w1h, b1, x1b, N, F);
  }
  // ---- layer 2: agg(x1b)[N,64] @ W2[64,128] -> x2b (bf16) ----
  {
    int tot = N * (F / 8);
    k_aggregate_b<3><<<(tot + 255) / 256, 256, 0, stream>>>(x1b, rs, epack, sn, aggh, N);
    dim3 g(2, (Mt + 1) / 2);
    k_gemm_rb<64, 2><<<g, 256, 0, stream>>>(aggh, w2h, b2, x2b, N, D2);
  }
  // ---- layer 3: agg(x2b)[N,128] @ W3[128,256] -> x3b (bf16) ----
  {
    int tot = N * (D2 / 8);
    k_aggregate_b<4><<<(tot + 255) / 256, 256, 0, stream>>>(x2b, rs, epack, sn, aggh, N);
    dim3 g(4, (Mt + 3) / 4);
    k_gemm_rb<128, 4><<<g, 256, 0, stream>>>(aggh, w3h, b3, x3b, N, D3);
  }

  // ---- pooling + head ----
  {
    dim3 g(PSPLIT, B);
    k_pool<<<g, C, 0, stream>>>(x3b, feature, gs, psum, D3, F);
  }
  {
    dim3 g((Hh + 255) / 256, B);
    k_fc1<<<g, 256, 0, stream>>>(psum, gs, Wf1, bf1, hid, C, Hh);
  }
  k_fc2  <<<B, 64, 0, stream>>>(hid, Wf2, bf2, out, Hh);
}

// Round 10
// 381.034 us; speedup vs baseline: 1.4115x; 1.4115x over previous
//
#include <hip/hip_runtime.h>
#include <cstdio>
#include <cstdint>

typedef _Float16 f16x8 __attribute__((ext_vector_type(8)));
typedef float f32x4 __attribute__((ext_vector_type(4)));

__device__ inline unsigned short f2bf(float f) {  // fp32 -> bf16 RNE
  unsigned u = __float_as_uint(f);
  u += 0x7fffu + ((u >> 16) & 1u);
  return (unsigned short)(u >> 16);
}
__device__ inline float bf2f(unsigned short h) {
  return __uint_as_float(((unsigned)h) << 16);
}
__device__ inline unsigned short f2h(float f) {   // fp32 -> fp16 RNE (bits)
  union { _Float16 h; unsigned short u; } cv;
  cv.h = (_Float16)f;
  return cv.u;
}

#define EPB 8192

// ======= fused prep: psum zero, feat->bf16, W->fp16^T, gbound, bhist ======
// NOTE (R9 lesson): do NOT add per-node cnt/wsum global atomics here --
// random-address atomics across XCD L2s serialized at ~80ns each (200us).
// cnt/wsum belongs in k_bprocA where sorted edges make it LDS-local.

__global__ __launch_bounds__(256)
void k_prep0(float* __restrict__ psum,
             const float* __restrict__ feature, ushort* __restrict__ featb,
             const float* __restrict__ W1, ushort* __restrict__ w1h,
             const float* __restrict__ W2, ushort* __restrict__ w2h,
             const float* __restrict__ W3, ushort* __restrict__ w3h,
             const int* __restrict__ pb, int* __restrict__ gs,
             const int* __restrict__ dst, int* __restrict__ H,
             int* __restrict__ rs,
             int BC, int NF, int F, int D2, int D3,
             int N, int B, int NB, int E,
             int nB, int nC, int nD, int nG) {
  __shared__ int hist[512];
  int b = blockIdx.x;
  int t = threadIdx.x;
  if (b < nB) {
    int i = b * 256 + t;
    if (i < BC) psum[i] = 0.f;
  } else if (b < nB + nC) {
    int base = ((b - nB) * 256 + t) * 4;
    if (base < NF) {
      float4 v = *reinterpret_cast<const float4*>(feature + base);
      ushort4 h;
      h.x = f2bf(v.x); h.y = f2bf(v.y); h.z = f2bf(v.z); h.w = f2bf(v.w);
      *reinterpret_cast<ushort4*>(featb + base) = h;
    }
  } else if (b < nB + nC + nD) {
    int idx = (b - nB - nC) * 256 + t;
    int s1 = F * F, s2 = s1 + F * D2, s3 = s2 + D2 * D3;
    if (idx < s1) {
      int k = idx / F, n = idx - k * F;
      w1h[(size_t)n * F + k] = f2h(W1[idx]);
    } else if (idx < s2) {
      int i2 = idx - s1; int k = i2 / D2, n = i2 - k * D2;
      w2h[(size_t)n * F + k] = f2h(W2[i2]);
    } else if (idx < s3) {
      int i3 = idx - s2; int k = i3 / D3, n = i3 - k * D3;
      w3h[(size_t)n * D2 + k] = f2h(W3[i3]);
    }
  } else if (b < nB + nC + nD + nG) {
    int bb = (b - nB - nC - nD) * 256 + t;
    if (bb == 0) rs[N] = E;            // row-end sentinel (absolute)
    if (bb <= B) {
      int lo = 0, hi = N;
      while (lo < hi) {
        int mid = (lo + hi) >> 1;
        if (pb[mid] < bb) lo = mid + 1; else hi = mid;
      }
      gs[bb] = lo;
    }
  } else {
    const int bi = b - nB - nC - nD - nG;
    for (int i = t; i < NB; i += 256) hist[i] = 0;
    __syncthreads();
    const int base = bi * EPB + t;
#pragma unroll
    for (int j = 0; j < EPB / 256; j++) {
      int e = base + 256 * j;
      if (e < E) atomicAdd(&hist[dst[e] >> 8], 1);
    }
    __syncthreads();
    for (int i = t; i < NB; i += 256) H[(size_t)bi * NB + i] = hist[i];
  }
}

// exclusive scan over T = NB*NBLK elems, CHUNK-LOCAL (chunk = 1024 = block).
__global__ __launch_bounds__(256)
void k_bscan1(const int* __restrict__ H, int* __restrict__ S,
              int* __restrict__ bsum, int NB, int NBLK, int T) {
  __shared__ int sh[256];
  const int t = threadIdx.x;
  const int base = blockIdx.x * 1024;
  int v[4]; int s = 0;
#pragma unroll
  for (int j = 0; j < 4; j++) {
    int idx = base + t * 4 + j;
    if (idx < T) {
      int bin = idx / NBLK, bi = idx - bin * NBLK;
      v[j] = H[(size_t)bi * NB + bin];
    } else v[j] = 0;
    s += v[j];
  }
  sh[t] = s;
  __syncthreads();
  for (int off = 1; off < 256; off <<= 1) {
    int x = (t >= off) ? sh[t - off] : 0;
    __syncthreads();
    sh[t] += x;
    __syncthreads();
  }
  int run = sh[t] - s;
#pragma unroll
  for (int j = 0; j < 4; j++) {
    int idx = base + t * 4 + j;
    if (idx < T) S[idx] = run;
    run += v[j];
  }
  if (t == 255) bsum[blockIdx.x] = sh[255];
}

// build exclusive chunk-prefix (<=512 chunks) in LDS: load + thread-0 scan
__device__ inline void build_prefix(const int* __restrict__ bsum, int nch,
                                    int* __restrict__ pre, int t) {
  for (int i = t; i < nch; i += 256) pre[i] = bsum[i];
  __syncthreads();
  if (t == 0) {
    int run = 0;
    for (int i = 0; i < nch; i++) { int v = pre[i]; pre[i] = run; run += v; }
  }
  __syncthreads();
}

// scatter edges into bucket-sorted order; ld packed into ssw.x bits 24..31
__global__ __launch_bounds__(256)
void k_bscatter(const int* __restrict__ src, const int* __restrict__ dst,
                const float* __restrict__ ew, const int* __restrict__ S,
                const int* __restrict__ bsb,
                int2* __restrict__ ssw,
                int NB, int NBLK, int E, int nchT) {
  __shared__ int cnt[512];
  __shared__ int sbase[512];
  __shared__ int pre[512];
  const int t = threadIdx.x, bi = blockIdx.x;
  build_prefix(bsb, nchT, pre, t);
  for (int i = t; i < NB; i += 256) {
    cnt[i] = 0;
    int j = i * NBLK + bi;
    sbase[i] = S[j] + pre[j >> 10];
  }
  __syncthreads();
  const int base = bi * EPB + t;
#pragma unroll
  for (int j = 0; j < EPB / 256; j++) {
    int e = base + 256 * j;
    if (e < E) {
      int d = dst[e];
      int bin = d >> 8;
      int r = atomicAdd(&cnt[bin], 1);
      int pos = sbase[bin] + r;
      ssw[pos] = make_int2(src[e] | ((d & 255) << 24), __float_as_int(ew[e]));
    }
  }
}

// per-bucket pass A: node counts + fp32 weighted degree, coalesced write.
__global__ __launch_bounds__(256)
void k_bprocA(const int2* __restrict__ ssw,
              const int* __restrict__ S, const int* __restrict__ bsb,
              int* __restrict__ cntN, float* __restrict__ wsumN,
              int NB, int NBLK, int N, int E, int nchT) {
  __shared__ int cnt[256];
  __shared__ float wsm[256];
  __shared__ int pre[512];
  const int t = threadIdx.x, bin = blockIdx.x;
  build_prefix(bsb, nchT, pre, t);
  cnt[t] = 0; wsm[t] = 0.f;
  __syncthreads();
  int j0 = bin * NBLK;
  const int start = S[j0] + pre[j0 >> 10];
  int end = E;
  if (bin + 1 < NB) { int j1 = (bin + 1) * NBLK; end = S[j1] + pre[j1 >> 10]; }
  for (int p = start + t; p < end; p += 256) {
    int2 sw = ssw[p];
    int ld = (unsigned)sw.x >> 24;
    atomicAdd(&cnt[ld], 1);
    atomicAdd(&wsm[ld], __int_as_float(sw.y));
  }
  __syncthreads();
  int n = bin * 256 + t;
  if (n < N) { cntN[n] = cnt[t]; wsumN[n] = wsm[t]; }
}

// scan of cntN -> rs (chunk-local) + bsum; dinv/selfnorm fused
__global__ __launch_bounds__(256)
void k_scan1(const int* __restrict__ cntN, const float* __restrict__ wsumN,
             int* __restrict__ rs, int* __restrict__ bsum,
             float* __restrict__ dinv, float* __restrict__ sn, int N) {
  __shared__ int sh[256];
  const int t = threadIdx.x;
  const int base = blockIdx.x * 1024;
  int v[4]; int s = 0;
#pragma unroll
  for (int j = 0; j < 4; j++) {
    int idx = base + t * 4 + j;
    if (idx < N) {
      v[j] = cntN[idx];
      double deg = 1.0 + (double)wsumN[idx];
      float r = (float)(1.0 / sqrt(deg));
      dinv[idx] = r;
      sn[idx] = r * r;
    } else v[j] = 0;
    s += v[j];
  }
  sh[t] = s;
  __syncthreads();
  for (int off = 1; off < 256; off <<= 1) {
    int x = (t >= off) ? sh[t - off] : 0;
    __syncthreads();
    sh[t] += x;
    __syncthreads();
  }
  int run = sh[t] - s;
#pragma unroll
  for (int j = 0; j < 4; j++) {
    int idx = base + t * 4 + j;
    if (idx < N) rs[idx] = run;
    run += v[j];
  }
  if (t == 255) bsum[blockIdx.x] = sh[255];
}

// per-bucket pass B: epack fill at absolute rs positions; writes ABSOLUTE rs
__global__ __launch_bounds__(256)
void k_bprocB(const int2* __restrict__ ssw,
              const int* __restrict__ S, const int* __restrict__ bsb,
              int* __restrict__ rs, const int* __restrict__ bsumN,
              const float* __restrict__ dinv,
              int2* __restrict__ epack,
              int NB, int NBLK, int N, int E, int nchT, int nchN) {
  __shared__ int cnt[256];
  __shared__ float sdv[256];
  __shared__ int srs[256];
  __shared__ int preT[512];
  __shared__ int preN[128];
  const int t = threadIdx.x, bin = blockIdx.x;
  for (int i = t; i < nchT; i += 256) preT[i] = bsb[i];
  for (int i = t; i < nchN; i += 256) preN[i] = bsumN[i];
  __syncthreads();
  if (t == 0) {
    int run = 0;
    for (int i = 0; i < nchT; i++) { int v = preT[i]; preT[i] = run; run += v; }
    run = 0;
    for (int i = 0; i < nchN; i++) { int v = preN[i]; preN[i] = run; run += v; }
  }
  __syncthreads();
  cnt[t] = 0;
  int n = bin * 256 + t;
  sdv[t] = (n < N) ? dinv[n] : 0.f;
  int rabs = 0;
  if (n < N) {
    rabs = rs[n] + preN[n >> 10];
    rs[n] = rabs;                      // absolute write-back
  }
  srs[t] = rabs;
  __syncthreads();
  int j0 = bin * NBLK;
  const int start = S[j0] + preT[j0 >> 10];
  int end = E;
  if (bin + 1 < NB) { int j1 = (bin + 1) * NBLK; end = S[j1] + preT[j1 >> 10]; }
  for (int p = start + t; p < end; p += 256) {
    int2 sw = ssw[p];
    int ld = (unsigned)sw.x >> 24;
    int sidx = sw.x & 0x00FFFFFF;
    int r = atomicAdd(&cnt[ld], 1);
    float w = dinv[sidx] * __int_as_float(sw.y) * sdv[ld];
    epack[srs[ld] + r] = make_int2(sidx, __float_as_int(w));
  }
}

// ================= CSR gather aggregation (bf16 in, fp16 out) ======

__device__ inline void bf8_fma(const int4 v, float w, float* acc) {
  acc[0] = fmaf(__uint_as_float((unsigned)v.x << 16), w, acc[0]);
  acc[1] = fmaf(__uint_as_float((unsigned)v.x & 0xffff0000u), w, acc[1]);
  acc[2] = fmaf(__uint_as_float((unsigned)v.y << 16), w, acc[2]);
  acc[3] = fmaf(__uint_as_float((unsigned)v.y & 0xffff0000u), w, acc[3]);
  acc[4] = fmaf(__uint_as_float((unsigned)v.z << 16), w, acc[4]);
  acc[5] = fmaf(__uint_as_float((unsigned)v.z & 0xffff0000u), w, acc[5]);
  acc[6] = fmaf(__uint_as_float((unsigned)v.w << 16), w, acc[6]);
  acc[7] = fmaf(__uint_as_float((unsigned)v.w & 0xffff0000u), w, acc[7]);
}

template<int LOG2L>
__global__ __launch_bounds__(256)
void k_aggregate_b(const ushort* __restrict__ Xb, const int* __restrict__ rs,
                   const int2* __restrict__ epack, const float* __restrict__ sn,
                   ushort* __restrict__ AH, int N) {
  const int t = blockIdx.x * blockDim.x + threadIdx.x;
  const int row = t >> LOG2L;
  if (row >= N) return;
  const int L = 1 << LOG2L;
  const int D = L << 3;
  const int c = (t & (L - 1)) << 3;
  const ushort* __restrict__ Xc = Xb + c;   // column-shifted base

  float acc[8];
  {
    int4 v = *reinterpret_cast<const int4*>(Xc + (size_t)row * D);
    float s = sn[row];
    acc[0] = s * __uint_as_float((unsigned)v.x << 16);
    acc[1] = s * __uint_as_float((unsigned)v.x & 0xffff0000u);
    acc[2] = s * __uint_as_float((unsigned)v.y << 16);
    acc[3] = s * __uint_as_float((unsigned)v.y & 0xffff0000u);
    acc[4] = s * __uint_as_float((unsigned)v.z << 16);
    acc[5] = s * __uint_as_float((unsigned)v.z & 0xffff0000u);
    acc[6] = s * __uint_as_float((unsigned)v.w << 16);
    acc[7] = s * __uint_as_float((unsigned)v.w & 0xffff0000u);
  }
  const int p0 = rs[row], pe = rs[row + 1];
  int i = p0;
  if ((i & 1) && i < pe) {          // peel to int4 alignment
    int2 e = epack[i];
    int4 v = *reinterpret_cast<const int4*>(Xc + (size_t)e.x * D);
    bf8_fma(v, __int_as_float(e.y), acc);
    i++;
  }
  for (; i + 8 <= pe; i += 8) {     // 8 gathers in flight
    int4 ea = *reinterpret_cast<const int4*>(&epack[i]);
    int4 eb = *reinterpret_cast<const int4*>(&epack[i + 2]);
    int4 ec = *reinterpret_cast<const int4*>(&epack[i + 4]);
    int4 ed = *reinterpret_cast<const int4*>(&epack[i + 6]);
    int4 v0 = *reinterpret_cast<const int4*>(Xc + (size_t)ea.x * D);
    int4 v1 = *reinterpret_cast<const int4*>(Xc + (size_t)ea.z * D);
    int4 v2 = *reinterpret_cast<const int4*>(Xc + (size_t)eb.x * D);
    int4 v3 = *reinterpret_cast<const int4*>(Xc + (size_t)eb.z * D);
    int4 v4 = *reinterpret_cast<const int4*>(Xc + (size_t)ec.x * D);
    int4 v5 = *reinterpret_cast<const int4*>(Xc + (size_t)ec.z * D);
    int4 v6 = *reinterpret_cast<const int4*>(Xc + (size_t)ed.x * D);
    int4 v7 = *reinterpret_cast<const int4*>(Xc + (size_t)ed.z * D);
    bf8_fma(v0, __int_as_float(ea.y), acc);
    bf8_fma(v1, __int_as_float(ea.w), acc);
    bf8_fma(v2, __int_as_float(eb.y), acc);
    bf8_fma(v3, __int_as_float(eb.w), acc);
    bf8_fma(v4, __int_as_float(ec.y), acc);
    bf8_fma(v5, __int_as_float(ec.w), acc);
    bf8_fma(v6, __int_as_float(ed.y), acc);
    bf8_fma(v7, __int_as_float(ed.w), acc);
  }
  if (i + 4 <= pe) {                // remainder 4
    int4 ea = *reinterpret_cast<const int4*>(&epack[i]);
    int4 eb = *reinterpret_cast<const int4*>(&epack[i + 2]);
    int4 v0 = *reinterpret_cast<const int4*>(Xc + (size_t)ea.x * D);
    int4 v1 = *reinterpret_cast<const int4*>(Xc + (size_t)ea.z * D);
    int4 v2 = *reinterpret_cast<const int4*>(Xc + (size_t)eb.x * D);
    int4 v3 = *reinterpret_cast<const int4*>(Xc + (size_t)eb.z * D);
    bf8_fma(v0, __int_as_float(ea.y), acc);
    bf8_fma(v1, __int_as_float(ea.w), acc);
    bf8_fma(v2, __int_as_float(eb.y), acc);
    bf8_fma(v3, __int_as_float(eb.w), acc);
    i += 4;
  }
  if (i + 2 <= pe) {                // remainder pair
    int4 e2 = *reinterpret_cast<const int4*>(&epack[i]);
    int4 v0 = *reinterpret_cast<const int4*>(Xc + (size_t)e2.x * D);
    int4 v1 = *reinterpret_cast<const int4*>(Xc + (size_t)e2.z * D);
    bf8_fma(v0, __int_as_float(e2.y), acc);
    bf8_fma(v1, __int_as_float(e2.w), acc);
    i += 2;
  }
  if (i < pe) {                     // remainder single
    int2 e = epack[i];
    int4 v = *reinterpret_cast<const int4*>(Xc + (size_t)e.x * D);
    bf8_fma(v, __int_as_float(e.y), acc);
  }
  ushort h[8];
#pragma unroll
  for (int j = 0; j < 8; j++) h[j] = f2h(acc[j]);
  size_t o = (size_t)row * D + c;
  *reinterpret_cast<ushort4*>(AH + o)     = make_ushort4(h[0], h[1], h[2], h[3]);
  *reinterpret_cast<ushort4*>(AH + o + 4) = make_ushort4(h[4], h[5], h[6], h[7]);
}

// ====== fp16 MFMA GEMM, B-in-registers, multi-tile blocks ======

template<int KT, int TPB>
__global__ __launch_bounds__(256, 3)
void k_gemm_rb(const ushort* __restrict__ Ah, const ushort* __restrict__ Bh,
               const float* __restrict__ bias, ushort* __restrict__ Y,
               int N, int D) {
  constexpr int NT = 64;
  constexpr int NK = KT / 32;
  const int t = threadIdx.x;
  const int wave = t >> 6, lane = t & 63;
  const int quad = lane >> 4, l16 = lane & 15;
  const int n0 = blockIdx.x * NT;
  const int mbase = blockIdx.y * (TPB * 128);

  f16x8 bf[NK][4];
#pragma unroll
  for (int k0 = 0; k0 < NK; k0++)
#pragma unroll
    for (int ni = 0; ni < 4; ni++)
      bf[k0][ni] = *reinterpret_cast<const f16x8*>(
          Bh + (size_t)(n0 + ni * 16 + l16) * KT + k0 * 32 + quad * 8);

  float bv[4];
#pragma unroll
  for (int ni = 0; ni < 4; ni++) bv[ni] = bias[n0 + ni * 16 + l16];

#pragma unroll 1
  for (int tile = 0; tile < TPB; tile++) {
    const int rt = mbase + tile * 128 + wave * 32 + l16;
    if (mbase + tile * 128 >= N) break;   // block-uniform
    int r0 = rt;      if (r0 >= N) r0 = N - 1;
    int r1 = rt + 16; if (r1 >= N) r1 = N - 1;
    const ushort* __restrict__ A0 = Ah + (size_t)r0 * KT + quad * 8;
    const ushort* __restrict__ A1 = Ah + (size_t)r1 * KT + quad * 8;

    f16x8 a0[NK], a1[NK];
#pragma unroll
    for (int k0 = 0; k0 < NK; k0++) {
      a0[k0] = *reinterpret_cast<const f16x8*>(A0 + k0 * 32);
      a1[k0] = *reinterpret_cast<const f16x8*>(A1 + k0 * 32);
    }

    f32x4 acc[2][4];
#pragma unroll
    for (int mi = 0; mi < 2; mi++)
#pragma unroll
      for (int ni = 0; ni < 4; ni++) acc[mi][ni] = (f32x4){0.f, 0.f, 0.f, 0.f};

#pragma unroll
    for (int k0 = 0; k0 < NK; k0++)
#pragma unroll
      for (int ni = 0; ni < 4; ni++) {
        acc[0][ni] = __builtin_amdgcn_mfma_f32_16x16x32_f16(a0[k0], bf[k0][ni], acc[0][ni], 0, 0, 0);
        acc[1][ni] = __builtin_amdgcn_mfma_f32_16x16x32_f16(a1[k0], bf[k0][ni], acc[1][ni], 0, 0, 0);
      }

    const int rb0 = mbase + tile * 128 + wave * 32 + quad * 4;
#pragma unroll
    for (int mi = 0; mi < 2; mi++) {
      int rb = rb0 + mi * 16;
#pragma unroll
      for (int ni = 0; ni < 4; ni++) {
        int col = n0 + ni * 16 + l16;
#pragma unroll
        for (int r = 0; r < 4; r++) {
          int row = rb + r;
          if (row < N)
            Y[(size_t)row * D + col] = f2bf(fmaxf(acc[mi][ni][r] + bv[ni], 0.f));
        }
      }
    }
  }
}

// ================= pooling: one (graph, split) per block, branch-free =====

#define PSPLIT 8

__global__ void k_pool(const ushort* __restrict__ X3b, const float* __restrict__ feat,
                       const int* __restrict__ gs, float* __restrict__ psum,
                       int D3, int F) {
  const int c = threadIdx.x;
  const int C = D3 + F;
  const int b = blockIdx.y;
  const int sp = blockIdx.x;
  const int s0 = gs[b], e0 = gs[b + 1];
  const int len = e0 - s0;
  if (len <= 0) return;
  const int chunk = (len + PSPLIT - 1) / PSPLIT;
  const int s = s0 + sp * chunk;
  int e = s + chunk; if (e > e0) e = e0;
  if (s >= e) return;
  const int n = e - s;
  float a0 = 0.f, a1 = 0.f, a2 = 0.f, a3 = 0.f;
  float a4 = 0.f, a5 = 0.f, a6 = 0.f, a7 = 0.f;
  if (c < D3) {
    const ushort* p = X3b + (size_t)s * D3 + c;
    int i = 0;
    for (; i + 8 <= n; i += 8) {
      a0 += bf2f(p[0 * (size_t)D3]);
      a1 += bf2f(p[1 * (size_t)D3]);
      a2 += bf2f(p[2 * (size_t)D3]);
      a3 += bf2f(p[3 * (size_t)D3]);
      a4 += bf2f(p[4 * (size_t)D3]);
      a5 += bf2f(p[5 * (size_t)D3]);
      a6 += bf2f(p[6 * (size_t)D3]);
      a7 += bf2f(p[7 * (size_t)D3]);
      p += 8 * (size_t)D3;
    }
    for (; i < n; i++) { a0 += bf2f(*p); p += D3; }
  } else {
    const float* p = feat + (size_t)s * F + (c - D3);
    int i = 0;
    for (; i + 8 <= n; i += 8) {
      a0 += p[0 * (size_t)F];
      a1 += p[1 * (size_t)F];
      a2 += p[2 * (size_t)F];
      a3 += p[3 * (size_t)F];
      a4 += p[4 * (size_t)F];
      a5 += p[5 * (size_t)F];
      a6 += p[6 * (size_t)F];
      a7 += p[7 * (size_t)F];
      p += 8 * (size_t)F;
    }
    for (; i < n; i++) { a0 += *p; p += F; }
  }
  float tot = ((a0 + a1) + (a2 + a3)) + ((a4 + a5) + (a6 + a7));
  atomicAdd(&psum[(size_t)b * C + c], tot);
}

// ================= FC head (gc normalization fused into fc1) ==============

__global__ __launch_bounds__(256)
void k_fc1(const float* __restrict__ psum, const int* __restrict__ gs,
           const float* __restrict__ Wf1, const float* __restrict__ bf1,
           float* __restrict__ hidden, int C, int Hh) {
  const int b = blockIdx.y;
  __shared__ float gcs[384];
  float invc = 1.f / fmaxf((float)(gs[b + 1] - gs[b]), 1.f);
  for (int c = threadIdx.x; c < C; c += 256)
    gcs[c] = psum[(size_t)b * C + c] * invc;
  __syncthreads();
  const int j = blockIdx.x * 256 + threadIdx.x;
  if (j >= Hh) return;
  const float* w = Wf1 + j;
  float a0 = 0.f, a1 = 0.f, a2 = 0.f, a3 = 0.f;
  int c = 0;
  for (; c + 4 <= C; c += 4) {
    a0 = fmaf(gcs[c + 0], w[(size_t)(c + 0) * Hh], a0);
    a1 = fmaf(gcs[c + 1], w[(size_t)(c + 1) * Hh], a1);
    a2 = fmaf(gcs[c + 2], w[(size_t)(c + 2) * Hh], a2);
    a3 = fmaf(gcs[c + 3], w[(size_t)(c + 3) * Hh], a3);
  }
  for (; c < C; c++) a0 = fmaf(gcs[c], w[(size_t)c * Hh], a0);
  float r = ((a0 + a1) + (a2 + a3)) + bf1[j];
  hidden[(size_t)b * Hh + j] = fmaxf(r, 0.f);
}

__global__ void k_fc2(const float* __restrict__ hidden, const float* __restrict__ Wf2,
                      const float* __restrict__ bf2, float* __restrict__ out, int Hh) {
  int b = blockIdx.x;
  int lane = threadIdx.x;  // 64
  double s = 0.0;
  for (int j = lane; j < Hh; j += 64) s += (double)hidden[(size_t)b * Hh + j] * (double)Wf2[j];
#pragma unroll
  for (int off = 32; off > 0; off >>= 1) s += __shfl_down(s, off);
  if (lane == 0) out[b] = (float)s + bf2[0];
}

// ================= launch =================

extern "C" void kernel_launch(void* const* d_in, const int* in_sizes, int n_in,
                              void* d_out, int out_size, void* d_ws, size_t ws_size,
                              hipStream_t stream) {
  const float* feature = (const float*)d_in[0];
  const int*   eidx    = (const int*)  d_in[1];
  const float* weight  = (const float*)d_in[2];
  const int*   pb      = (const int*)  d_in[3];
  const float* W1  = (const float*)d_in[4];
  const float* b1  = (const float*)d_in[5];
  const float* W2  = (const float*)d_in[6];
  const float* b2  = (const float*)d_in[7];
  const float* W3  = (const float*)d_in[8];
  const float* b3  = (const float*)d_in[9];
  const float* Wf1 = (const float*)d_in[10];
  const float* bf1 = (const float*)d_in[11];
  const float* Wf2 = (const float*)d_in[12];
  const float* bf2 = (const float*)d_in[13];

  const int F  = in_sizes[5];          // 64
  const int D2 = in_sizes[7];          // 128
  const int D3 = in_sizes[9];          // 256
  const int Hh = in_sizes[11];         // 1024
  const int N  = in_sizes[0] / F;      // 100000
  const int E  = in_sizes[1] / 2;      // 1200000
  const int B  = out_size;             // 256
  const int C  = D3 + F;               // 320

  const int* srcp = eidx;
  const int* dstp = eidx + E;

  const int NB   = (N + 255) / 256;        // buckets (<=512)
  const int NBLK = (E + EPB - 1) / EPB;    // edge blocks
  const int T    = NB * NBLK;              // scan length
  const int nchT = (T + 1023) / 1024;      // T-scan chunks (<=512)
  const int nchN = (N + 1023) / 1024;      // rs-scan chunks (<=128)

  auto al = [](size_t x) { return (x + 255) & ~(size_t)255; };
  size_t off = 0;
  auto alloc = [&](size_t bytes) { size_t o = off; off += al(bytes); return o; };
  size_t o_H     = alloc((size_t)T * 4);
  size_t o_S     = alloc((size_t)T * 4);
  size_t o_bsb   = alloc((size_t)nchT * 4);
  size_t o_ssw   = alloc((size_t)E * 8);
  size_t o_cntN  = alloc((size_t)N * 4);
  size_t o_wsumN = alloc((size_t)N * 4);
  size_t o_dinv  = alloc((size_t)N * 4);
  size_t o_sn    = alloc((size_t)N * 4);
  size_t o_rs    = alloc((size_t)(N + 1) * 4);
  size_t o_bsum  = alloc((size_t)nchN * 4);
  size_t o_epack = alloc((size_t)E * 8);
  size_t o_featb = alloc((size_t)N * F  * 2);
  size_t o_x1b   = alloc((size_t)N * F  * 2);
  size_t o_x2b   = alloc((size_t)N * D2 * 2);
  size_t o_x3b   = alloc((size_t)N * D3 * 2);
  size_t o_aggh  = alloc((size_t)N * D2 * 2);   // fp16 (max K = 128)
  size_t o_w1h   = alloc((size_t)F  * F  * 2);
  size_t o_w2h   = alloc((size_t)F  * D2 * 2);
  size_t o_w3h   = alloc((size_t)D2 * D3 * 2);
  size_t o_psum  = alloc((size_t)B * C * 4);    // float
  size_t o_gs    = alloc((size_t)(B + 1) * 4);
  size_t o_hid   = alloc((size_t)B * Hh * 4);
  if (off > ws_size) {
    fprintf(stderr, "kernel_launch: workspace too small: need %zu, have %zu\n", off, ws_size);
    return;
  }

  char* ws = (char*)d_ws;
  int*    H     = (int*)  (ws + o_H);
  int*    S     = (int*)  (ws + o_S);
  int*    bsb   = (int*)  (ws + o_bsb);
  int2*   ssw   = (int2*) (ws + o_ssw);
  int*    cntN  = (int*)  (ws + o_cntN);
  float*  wsumN = (float*)(ws + o_wsumN);
  float*  dinv  = (float*)(ws + o_dinv);
  float*  sn    = (float*)(ws + o_sn);
  int*    rs    = (int*)  (ws + o_rs);
  int*    bsum  = (int*)  (ws + o_bsum);
  int2*   epack = (int2*) (ws + o_epack);
  ushort* featb = (ushort*)(ws + o_featb);
  ushort* x1b   = (ushort*)(ws + o_x1b);
  ushort* x2b   = (ushort*)(ws + o_x2b);
  ushort* x3b   = (ushort*)(ws + o_x3b);
  ushort* aggh  = (ushort*)(ws + o_aggh);
  ushort* w1h   = (ushort*)(ws + o_w1h);
  ushort* w2h   = (ushort*)(ws + o_w2h);
  ushort* w3h   = (ushort*)(ws + o_w3h);
  float*  psum  = (float*) (ws + o_psum);
  int*    gs    = (int*)  (ws + o_gs);
  float*  hid   = (float*)(ws + o_hid);
  float*  out   = (float*)d_out;

  // ---- fused prep (+gbound +bhist) ----
  const int BC = B * C, NF = N * F;
  const int nB = (BC + 255) / 256;
  const int nC = (NF / 4 + 255) / 256;
  const int nD = (F * F + F * D2 + D2 * D3 + 255) / 256;
  const int nG = (B + 1 + 255) / 256;
  k_prep0<<<nB + nC + nD + nG + NBLK, 256, 0, stream>>>(
      psum, feature, featb, W1, w1h, W2, w2h, W3, w3h,
      pb, gs, dstp, H, rs,
      BC, NF, F, D2, D3, N, B, NB, E, nB, nC, nD, nG);

  // ---- sort-based CSR build (chunk-local scans, consumer fixup) ----
  k_bscan1  <<<nchT, 256, 0, stream>>>(H, S, bsb, NB, NBLK, T);
  k_bscatter<<<NBLK, 256, 0, stream>>>(srcp, dstp, weight, S, bsb, ssw, NB, NBLK, E, nchT);
  k_bprocA  <<<NB, 256, 0, stream>>>(ssw, S, bsb, cntN, wsumN, NB, NBLK, N, E, nchT);
  k_scan1   <<<nchN, 256, 0, stream>>>(cntN, wsumN, rs, bsum, dinv, sn, N);
  k_bprocB  <<<NB, 256, 0, stream>>>(ssw, S, bsb, rs, bsum, dinv, epack, NB, NBLK, N, E, nchT, nchN);

  const int Mt = (N + 127) / 128;   // 128-row M-tiles

  // ---- layer 1: agg(featb)[N,64] @ W1[64,64] -> x1b (bf16) ----
  {
    int tot = N * (F / 8);
    k_aggregate_b<3><<<(tot + 255) / 256, 256, 0, stream>>>(featb, rs, epack, sn, aggh, N);
    dim3 g(1, Mt);
    k_gemm_rb<64, 1><<<g, 256, 0, stream>>>(aggh, w1h, b1, x1b, N, F);
  }
  // ---- layer 2: agg(x1b)[N,64] @ W2[64,128] -> x2b (bf16) ----
  {
    int tot = N * (F / 8);
    k_aggregate_b<3><<<(tot + 255) / 256, 256, 0, stream>>>(x1b, rs, epack, sn, aggh, N);
    dim3 g(2, (Mt + 1) / 2);
    k_gemm_rb<64, 2><<<g, 256, 0, stream>>>(aggh, w2h, b2, x2b, N, D2);
  }
  // ---- layer 3: agg(x2b)[N,128] @ W3[128,256] -> x3b (bf16) ----
  {
    int tot = N * (D2 / 8);
    k_aggregate_b<4><<<(tot + 255) / 256, 256, 0, stream>>>(x2b, rs, epack, sn, aggh, N);
    dim3 g(4, (Mt + 3) / 4);
    k_gemm_rb<128, 4><<<g, 256, 0, stream>>>(aggh, w3h, b3, x3b, N, D3);
  }

  // ---- pooling + head ----
  {
    dim3 g(PSPLIT, B);
    k_pool<<<g, C, 0, stream>>>(x3b, feature, gs, psum, D3, F);
  }
  {
    dim3 g((Hh + 255) / 256, B);
    k_fc1<<<g, 256, 0, stream>>>(psum, gs, Wf1, bf1, hid, C, Hh);
  }
  k_fc2  <<<B, 64, 0, stream>>>(hid, Wf2, bf2, out, Hh);
}